// Round 10
// baseline (173.324 us; speedup 1.0000x reference)
//
#include <hip/hip_runtime.h>

#define MDIM 512
#define NDIM 8192
#define KDIM 8192

typedef float v4f __attribute__((ext_vector_type(4)));
typedef int   v4i __attribute__((ext_vector_type(4)));
typedef char  c16 __attribute__((ext_vector_type(16)));

// Fragment-major unit layout (16B = one lane's MFMA operand slice for
// mfma_i32_16x16x64_i8). Within a (row-tile rt of 16, k64-tile kt):
//   unit(frag fb, lane l16, kgrp g) at byte fb*1024 + l16*64 + g*16
// MFMA operand read: lane l -> l16 = l&15, g = l>>4 -> per-lane addr
// base + (l&15)*64 + (l>>4)*16. A tiles: 8 frags (128 rows) = 8KB;
// B tiles: 4 frags (64 rows) = 4KB.

// wq int32 -> int8 frag-major. Reads fully dense (thread = 16 ints of one
// row); writes 16B units (64B-chunk granularity, HBM burst = 64B, fine).
__global__ __launch_bounds__(256) void compress_w_kernel(
    const int* __restrict__ wq, char* __restrict__ w8) {
  const int tid = blockIdx.x * 256 + threadIdx.x;
  const int R = tid >> 9;     // weight row 0..8191
  const int k16 = tid & 511;  // 16-int group in row
  const int* src = wq + ((size_t)R << 13) + k16 * 16;
  v4i a[4];
#pragma unroll
  for (int h = 0; h < 4; ++h) a[h] = *(const v4i*)(src + h * 4);
  c16 q;
#pragma unroll
  for (int h = 0; h < 4; ++h) {
    q[h * 4 + 0] = (char)a[h][0];
    q[h * 4 + 1] = (char)a[h][1];
    q[h * 4 + 2] = (char)a[h][2];
    q[h * 4 + 3] = (char)a[h][3];
  }
  const int nt = R >> 6, nb = (R & 63) >> 4, l = R & 15;
  const int kt = k16 >> 2, g = k16 & 3;
  *(c16*)(w8 + ((size_t)(nt * 128 + kt) << 12) + nb * 1024 + l * 64 + g * 16) = q;
}

// x fp32 -> int8 with per-row scale ax[m], frag-major xq[mt4][kt128][8KB].
__global__ __launch_bounds__(256) void quant_x_kernel(
    const float* __restrict__ x, char* __restrict__ xq, float* __restrict__ ax) {
  const int m = blockIdx.x;
  const int t = threadIdx.x;
  const float* row = x + ((size_t)m << 13);
  v4f v[8];
  float mx = 0.f;
#pragma unroll
  for (int i = 0; i < 8; ++i) {
    v[i] = *(const v4f*)(row + t * 32 + i * 4);
#pragma unroll
    for (int r = 0; r < 4; ++r) mx = fmaxf(mx, fabsf(v[i][r]));
  }
#pragma unroll
  for (int d = 1; d < 64; d <<= 1) mx = fmaxf(mx, __shfl_xor(mx, d));
  __shared__ float smx[4];
  if ((t & 63) == 0) smx[t >> 6] = mx;
  __syncthreads();
  mx = fmaxf(fmaxf(smx[0], smx[1]), fmaxf(smx[2], smx[3]));
  const float inv = (mx > 0.f) ? 127.f / mx : 0.f;
  if (t == 0) ax[m] = mx / 127.f;
  const int mt = m >> 7, mb = (m & 127) >> 4, l = m & 15;
#pragma unroll
  for (int g2 = 0; g2 < 2; ++g2) {
    c16 q;
#pragma unroll
    for (int e = 0; e < 16; ++e) {
      const int idx = g2 * 4 + (e >> 2);
      float f = fminf(fmaxf(v[idx][e & 3] * inv, -127.f), 127.f);
      q[e] = (char)__float2int_rn(f);
    }
    const int k16 = t * 2 + g2;
    const int kt = k16 >> 2, g = k16 & 3;
    *(c16*)(xq + ((size_t)(mt * 128 + kt) << 13) + mb * 1024 + l * 64 + g * 16) = q;
  }
}

template <int KS>
__global__ __launch_bounds__(256) void reduce_kernel(const float* __restrict__ p,
                                                     float* __restrict__ out) {
  const size_t i = ((size_t)blockIdx.x * 256 + threadIdx.x) * 4;
  v4f a = *(const v4f*)(p + i);
#pragma unroll
  for (int s = 1; s < KS; ++s) a += *(const v4f*)(p + (size_t)s * MDIM * NDIM + i);
  *(v4f*)(out + i) = a;
}

// Pure-i8 GEMM, NO LDS / NO barriers: both operands read as fragment-major
// 16B/lane global loads straight from L2/L3 (w8 64MB + xq 4MB are
// cache-resident after the producer passes). Per k128 step per wave:
// 12 loads + 16 mfma_i32_16x16x64_i8 + scale fold. Latency hidden by
// 12 waves/CU TLP + unconstrained compiler load hoisting.
template <int KS>
__global__ __launch_bounds__(256, 3) void gemm_i8_kernel(
    const char* __restrict__ xq, const char* __restrict__ w8,
    const float* __restrict__ wsc, const float* __restrict__ ax,
    float* __restrict__ outp) {
  constexpr int NSTEP = 64 / KS;  // k128 steps per block

  // XCD swizzle: XCD c owns nt in [c*16, c*16+16) x all mt,kh -> B frags
  // shared 4x (mt) in that XCD's L2/L3 slice.
  const int b = blockIdx.x;
  const int c = b & 7;
  const int s = b >> 3;
  const int mt = s & 3;
  const int kh = (KS > 1) ? ((s >> 2) & (KS - 1)) : 0;
  const int nt = c * 16 + (s >> (KS > 1 ? 3 : 2));
  const int m0 = mt * 128, n0 = nt * 64;
  const int kt0 = kh * (128 / KS);  // k64-tile base

  const int t = threadIdx.x;
  const int w = t >> 6, l = t & 63;
  const int wm = (w >> 1) * 64, wn = (w & 1) * 32;
  const int lofs = (l & 15) * 64 + (l >> 4) * 16;  // per-lane frag offset

  const char* ap = xq + (((size_t)(mt * 128 + kt0)) << 13) + (wm >> 4) * 1024 + lofs;
  const char* bp = w8 + (((size_t)(nt * 128 + kt0)) << 12) + (wn >> 4) * 1024 + lofs;
  const float* scp = wsc + (nt >> 1) * 64 + (kt0 >> 1);

  v4i acc[4][2] = {};
  v4f facc[4][2] = {};

#pragma unroll 1
  for (int tt = 0; tt < NSTEP; ++tt) {
#pragma unroll
    for (int kk = 0; kk < 2; ++kk) {  // two k64 halves of the scale block
      v4i af[4], bq[2];
#pragma unroll
      for (int i = 0; i < 4; ++i)
        af[i] = *(const v4i*)(ap + kk * 8192 + i * 1024);
#pragma unroll
      for (int j = 0; j < 2; ++j)
        bq[j] = *(const v4i*)(bp + kk * 4096 + j * 1024);
#pragma unroll
      for (int i = 0; i < 4; ++i)
#pragma unroll
        for (int j = 0; j < 2; ++j)
          acc[i][j] = __builtin_amdgcn_mfma_i32_16x16x64_i8(
              af[i], bq[j], acc[i][j], 0, 0, 0);
    }
    const float sc = scp[tt];  // one (n128, k128) scale block per step
#pragma unroll
    for (int i = 0; i < 4; ++i)
#pragma unroll
      for (int j = 0; j < 2; ++j) {
#pragma unroll
        for (int r = 0; r < 4; ++r)
          facc[i][j][r] = fmaf(sc, (float)acc[i][j][r], facc[i][j][r]);
        acc[i][j] = v4i{0, 0, 0, 0};
      }
    ap += 16384;  // 2 k64 A-tiles
    bp += 8192;   // 2 k64 B-tiles
  }

  float* dst = outp + ((KS > 1) ? (size_t)kh * MDIM * NDIM : 0);
#pragma unroll
  for (int i = 0; i < 4; ++i) {
    const int mrow = m0 + wm + i * 16 + (l >> 4) * 4;
#pragma unroll
    for (int j = 0; j < 2; ++j) {
      const int ocol = n0 + wn + j * 16 + (l & 15);
#pragma unroll
      for (int r = 0; r < 4; ++r)
        dst[(size_t)(mrow + r) * NDIM + ocol] = ax[mrow + r] * facc[i][j][r];
    }
  }
}

extern "C" void kernel_launch(void* const* d_in, const int* in_sizes, int n_in,
                              void* d_out, int out_size, void* d_ws,
                              size_t ws_size, hipStream_t stream) {
  const float* x = (const float*)d_in[0];
  const int* wq = (const int*)d_in[1];
  const float* wsc = (const float*)d_in[2];
  float* out = (float*)d_out;

  const size_t W8 = (size_t)NDIM * KDIM;      // 64 MB
  const size_t XQ = (size_t)MDIM * KDIM;      // 4 MB
  const size_t AX = 65536;                    // padded
  const size_t PS = (size_t)MDIM * NDIM * 4;  // 16 MB per partial

  char* w8 = (char*)d_ws;
  char* xq = (char*)d_ws + W8;
  float* ax = (float*)((char*)d_ws + W8 + XQ);
  float* part = (float*)((char*)d_ws + W8 + XQ + AX);

  compress_w_kernel<<<dim3((NDIM * (KDIM / 16)) / 256), dim3(256), 0, stream>>>(wq, w8);
  quant_x_kernel<<<dim3(MDIM), dim3(256), 0, stream>>>(x, xq, ax);

  if (ws_size >= W8 + XQ + AX + 2 * PS) {
    gemm_i8_kernel<2><<<dim3(1024), dim3(256), 0, stream>>>(xq, w8, wsc, ax, part);
    reduce_kernel<2><<<dim3((MDIM * NDIM) / (256 * 4)), dim3(256), 0, stream>>>(part, out);
  } else {
    gemm_i8_kernel<1><<<dim3(512), dim3(256), 0, stream>>>(xq, w8, wsc, ax, out);
  }
}

// Round 11
// 154.351 us; speedup vs baseline: 1.1229x; 1.1229x over previous
//
#include <hip/hip_runtime.h>

#define MDIM 512
#define NDIM 8192
#define KDIM 8192

typedef float v4f __attribute__((ext_vector_type(4)));
typedef int   v4i __attribute__((ext_vector_type(4)));
typedef char  c16 __attribute__((ext_vector_type(16)));

#define GLDS16(g, l)                                                    \
  __builtin_amdgcn_global_load_lds(                                     \
      (const __attribute__((address_space(1))) void*)(g),               \
      (__attribute__((address_space(3))) void*)(l), 16, 0, 0)
#define SB __builtin_amdgcn_sched_barrier(0)

// Swizzled byte offset inside a tile of 64B rows (BK=64 int8): rows paired
// into 128B blocks of 8x16B slots; slot XOR'd with row-pair (r8 scheme,
// measured best). Producers write this layout; glds copies linearly;
// gemm ds_read applies the same formula (rule 21: both sides).
__device__ __forceinline__ int swb(int row, int g) {
  return ((row >> 1) << 7) + (((((row & 1) << 2) | g) ^ ((row >> 1) & 7)) << 4);
}

// Merged producer:
//  blocks [0, 16384): wq int32 -> int8, tiled w8[nt128][kt128][4KB], swizzled.
//  blocks [16384, 16896): x fp32 -> int8 + per-row scale ax, xq tiled.
__global__ __launch_bounds__(256) void produce_kernel(
    const int* __restrict__ wq, const float* __restrict__ x,
    char* __restrict__ w8, char* __restrict__ xq, float* __restrict__ ax) {
  if (blockIdx.x < 16384) {
    const int tid = blockIdx.x * 256 + threadIdx.x;
    const int R = tid >> 9;     // weight row 0..8191
    const int k16 = tid & 511;  // 16-int group
    const int* src = wq + ((size_t)R << 13) + k16 * 16;
    v4i a[4];
#pragma unroll
    for (int h = 0; h < 4; ++h) a[h] = *(const v4i*)(src + h * 4);
    c16 q;
#pragma unroll
    for (int h = 0; h < 4; ++h) {
      q[h * 4 + 0] = (char)a[h][0];
      q[h * 4 + 1] = (char)a[h][1];
      q[h * 4 + 2] = (char)a[h][2];
      q[h * 4 + 3] = (char)a[h][3];
    }
    const int nt = R >> 6, r = R & 63;
    const int kt = k16 >> 2, g = k16 & 3;
    *(c16*)(w8 + ((size_t)(nt * 128 + kt) << 12) + swb(r, g)) = q;
  } else {
    const int m = blockIdx.x - 16384;
    const int t = threadIdx.x;
    const float* row = x + ((size_t)m << 13);
    v4f v[8];
    float mx = 0.f;
#pragma unroll
    for (int i = 0; i < 8; ++i) {
      v[i] = *(const v4f*)(row + t * 32 + i * 4);
#pragma unroll
      for (int r = 0; r < 4; ++r) mx = fmaxf(mx, fabsf(v[i][r]));
    }
#pragma unroll
    for (int d = 1; d < 64; d <<= 1) mx = fmaxf(mx, __shfl_xor(mx, d));
    __shared__ float smx[4];
    if ((t & 63) == 0) smx[t >> 6] = mx;
    __syncthreads();
    mx = fmaxf(fmaxf(smx[0], smx[1]), fmaxf(smx[2], smx[3]));
    const float inv = (mx > 0.f) ? 127.f / mx : 0.f;
    if (t == 0) ax[m] = mx / 127.f;
    const int mt = m >> 7, r = m & 127;
#pragma unroll
    for (int g2 = 0; g2 < 2; ++g2) {
      c16 q;
#pragma unroll
      for (int e = 0; e < 16; ++e) {
        const int idx = g2 * 4 + (e >> 2);
        float f = fminf(fmaxf(v[idx][e & 3] * inv, -127.f), 127.f);
        q[e] = (char)__float2int_rn(f);
      }
      const int k16 = t * 2 + g2;
      const int kt = k16 >> 2, g = k16 & 3;
      *(c16*)(xq + ((size_t)(mt * 128 + kt) << 13) + swb(r, g)) = q;
    }
  }
}

// Pure-i8 GEMM (r8 structure, best measured), upgraded: KS=1 (direct store,
// no partials/reduce) and TRIPLE-buffered LDS -> prefetch lead = 2 phases
// (uniform counted vmcnt(6), never 0 mid-loop). BM=128 BN=64 BK=64,
// 4 waves (64m x 32n each); per phase/wave: 3 glds, 6 ds_read_b128,
// 8 mfma_i32_16x16x64_i8; scale fold per k128 (2 phases); ax at epilogue.
__global__ __launch_bounds__(256, 2) void gemm_i8_kernel(
    const char* __restrict__ xq, const char* __restrict__ w8,
    const float* __restrict__ wsc, const float* __restrict__ ax,
    float* __restrict__ out) {
  constexpr int NKT = 128;       // k64 phases
  __shared__ char lA[3][8192];   // 24 KB
  __shared__ char lB[3][4096];   // 12 KB

  // XCD swizzle: XCD c owns nt in [c*16, c*16+16) x all 4 mt -> each weight
  // tile served to 4 mt-blocks from that XCD's L2.
  const int b = blockIdx.x;
  const int c = b & 7;
  const int s = b >> 3;  // 0..63
  const int mt = s & 3;
  const int nt = c * 16 + (s >> 2);
  const int m0 = mt * 128, n0 = nt * 64;

  const int t = threadIdx.x;
  const int w = t >> 6, l = t & 63;
  const int wm = (w >> 1) * 64, wn = (w & 1) * 32;
  const int l15 = l & 15, q = l >> 4;

  const char* asrc = xq + ((size_t)(mt * 128) << 13);
  const char* bsrc = w8 + ((size_t)(nt * 128) << 12);

  v4i acc[4][2] = {};
  v4f facc[4][2] = {};

  auto issue = [&](int tt) {
    const int buf = tt % 3;
#pragma unroll
    for (int it = 0; it < 2; ++it) {
      const int ub = (it * 4 + w) * 64;  // wave-uniform 16B-unit base
      GLDS16(asrc + ((size_t)tt << 13) + (size_t)(ub + l) * 16, &lA[buf][ub * 16]);
    }
    GLDS16(bsrc + ((size_t)tt << 12) + (size_t)(w * 64 + l) * 16, &lB[buf][w * 1024]);
  };

  issue(0);
  issue(1);
#pragma unroll 1
  for (int tt = 0; tt < NKT; ++tt) {
    const int cur = tt % 3;
    SB;
    __builtin_amdgcn_s_barrier();  // all waves done reading buf[cur] (t-3)
    SB;
    if (tt + 2 < NKT) {
      issue(tt + 2);  // -> buf[(tt+2)%3]; stays in flight 2 phases
      SB;
      asm volatile("s_waitcnt vmcnt(6)" ::: "memory");  // tile tt landed
    } else if (tt + 1 < NKT) {
      asm volatile("s_waitcnt vmcnt(3)" ::: "memory");
    } else {
      asm volatile("s_waitcnt vmcnt(0)" ::: "memory");
    }
    SB;
    __builtin_amdgcn_s_barrier();  // buf[cur] visible to all waves
    SB;

    v4i af[4], bq[2];
#pragma unroll
    for (int i = 0; i < 4; ++i)
      af[i] = *(const v4i*)&lA[cur][swb(wm + i * 16 + l15, q)];
#pragma unroll
    for (int j = 0; j < 2; ++j)
      bq[j] = *(const v4i*)&lB[cur][swb(wn + j * 16 + l15, q)];
#pragma unroll
    for (int i = 0; i < 4; ++i)
#pragma unroll
      for (int j = 0; j < 2; ++j)
        acc[i][j] = __builtin_amdgcn_mfma_i32_16x16x64_i8(
            af[i], bq[j], acc[i][j], 0, 0, 0);

    if (tt & 1) {  // per-k128 scale block -> fold into f32 accumulator
      const float sc = wsc[(nt >> 1) * 64 + (tt >> 1)];
#pragma unroll
      for (int i = 0; i < 4; ++i)
#pragma unroll
        for (int j = 0; j < 2; ++j) {
#pragma unroll
          for (int r = 0; r < 4; ++r)
            facc[i][j][r] = fmaf(sc, (float)acc[i][j][r], facc[i][j][r]);
          acc[i][j] = v4i{0, 0, 0, 0};
        }
    }
  }

#pragma unroll
  for (int i = 0; i < 4; ++i) {
    const int mrow = m0 + wm + i * 16 + (l >> 4) * 4;
#pragma unroll
    for (int j = 0; j < 2; ++j) {
      const int ocol = n0 + wn + j * 16 + l15;
#pragma unroll
      for (int r = 0; r < 4; ++r)
        out[(size_t)(mrow + r) * NDIM + ocol] = ax[mrow + r] * facc[i][j][r];
    }
  }
}

extern "C" void kernel_launch(void* const* d_in, const int* in_sizes, int n_in,
                              void* d_out, int out_size, void* d_ws,
                              size_t ws_size, hipStream_t stream) {
  const float* x = (const float*)d_in[0];
  const int* wq = (const int*)d_in[1];
  const float* wsc = (const float*)d_in[2];
  float* out = (float*)d_out;

  const size_t W8 = (size_t)NDIM * KDIM;  // 64 MB
  const size_t XQ = (size_t)MDIM * KDIM;  // 4 MB

  char* w8 = (char*)d_ws;
  char* xq = (char*)d_ws + W8;
  float* ax = (float*)((char*)d_ws + W8 + XQ);

  produce_kernel<<<dim3(16384 + MDIM), dim3(256), 0, stream>>>(wq, x, w8, xq, ax);
  gemm_i8_kernel<<<dim3(512), dim3(256), 0, stream>>>(xq, w8, wsc, ax, out);
}